// Round 4
// baseline (372.499 us; speedup 1.0000x reference)
//
#include <hip/hip_runtime.h>
#include <hip/hip_bf16.h>
#include <stdint.h>

#define NN 10000
#define NF 256
#define NSTEPS 313   // ceil(10000/32)
#define NSP 8        // K-split factor

typedef float f32x4 __attribute__((ext_vector_type(4)));
typedef __bf16 bf16x8 __attribute__((ext_vector_type(8)));
typedef unsigned short u16;

__device__ __forceinline__ u16 f2bf(float f) {
    __bf16 h = (__bf16)f;
    return __builtin_bit_cast(u16, h);
}

// ---------------- kernel 1: deg -> dinv ----------------
__global__ __launch_bounds__(256) void k_deg(const float* __restrict__ adj,
                                             float* __restrict__ dinv) {
    const int row = blockIdx.x;
    const f32x4* rp = reinterpret_cast<const f32x4*>(adj + (size_t)row * NN);
    float s = 0.f;
    for (int j = threadIdx.x; j < NN / 4; j += 256) {
        f32x4 v = rp[j];
        s += (v[0] + v[1]) + (v[2] + v[3]);
    }
#pragma unroll
    for (int off = 32; off > 0; off >>= 1) s += __shfl_down(s, off, 64);
    __shared__ float red[4];
    const int lane = threadIdx.x & 63, w = threadIdx.x >> 6;
    if (lane == 0) red[w] = s;
    __syncthreads();
    if (threadIdx.x == 0) {
        float deg = (red[0] + red[1]) + (red[2] + red[3]);
        dinv[row] = deg > 0.f ? 1.0f / sqrtf(deg) : 0.0f;
    }
}

// ---------------- kernel 2: T = feat @ W; SPT = (dinv*T)^T bf16; acc0 = 2*dinv^2*T + b ----------------
__global__ __launch_bounds__(256) void k_support(const float* __restrict__ feat,
                                                 const float* __restrict__ W,
                                                 const float* __restrict__ dinv,
                                                 const float* __restrict__ bias,
                                                 u16* __restrict__ SPT,
                                                 float* __restrict__ accbuf) {
    const int j0 = blockIdx.x * 64;
    const int c0 = blockIdx.y * 64;
    __shared__ float flds[128][64];   // [f][r] transposed, 32 KB
    const int t = threadIdx.x;
    const int rg = t & 15, cg = t >> 4;
    const int sr = t >> 2, sf = (t & 3) * 32;
    float acc[4][4] = {};

    for (int half = 0; half < 2; ++half) {
        __syncthreads();
        const int gj = j0 + sr;
#pragma unroll
        for (int i = 0; i < 8; ++i) {
            f32x4 v = {};
            if (gj < NN)
                v = *reinterpret_cast<const f32x4*>(&feat[(size_t)gj * NF + half * 128 + sf + i * 4]);
#pragma unroll
            for (int u = 0; u < 4; ++u) flds[sf + i * 4 + u][sr] = v[u];
        }
        __syncthreads();
#pragma unroll 4
        for (int f = 0; f < 128; ++f) {
            f32x4 fv = *reinterpret_cast<const f32x4*>(&flds[f][rg * 4]);
            f32x4 wv = *reinterpret_cast<const f32x4*>(&W[(size_t)(half * 128 + f) * NF + c0 + cg * 4]);
#pragma unroll
            for (int r = 0; r < 4; ++r)
#pragma unroll
                for (int c = 0; c < 4; ++c)
                    acc[r][c] = fmaf(fv[r], wv[c], acc[r][c]);
        }
    }

    const int jb = j0 + rg * 4;
    if (jb < NN) {
        const f32x4 bv = *reinterpret_cast<const f32x4*>(&bias[c0 + cg * 4]);
        u16 bits[4][4];
#pragma unroll
        for (int r = 0; r < 4; ++r) {
            const float dv = dinv[jb + r];
            f32x4 init;
#pragma unroll
            for (int c = 0; c < 4; ++c) {
                const float sp = acc[r][c] * dv;          // S' = dinv_j * T
                bits[r][c] = f2bf(sp);
                init[c] = 2.f * dv * sp + bv[c];          // self-term + bias (fp32)
            }
            *reinterpret_cast<f32x4*>(&accbuf[(size_t)(jb + r) * NF + c0 + cg * 4]) = init;
        }
#pragma unroll
        for (int c = 0; c < 4; ++c) {
            ushort4 v; v.x = bits[0][c]; v.y = bits[1][c]; v.z = bits[2][c]; v.w = bits[3][c];
            *reinterpret_cast<ushort4*>(&SPT[(size_t)(c0 + cg * 4 + c) * NN + jb]) = v;
        }
    }
}

// ---------------- kernel 3: accbuf += dinv_i * adj(tile) @ S'  (bf16 MFMA, barrier-free) ----------------
// grid (40, 4, NSP). Block = 4 waves; wave w owns rows [mt*256+w*64, +64) x cols [nt*64, +64).
// A: per-lane global->reg in MFMA layout. B: per-lane from L2-resident SPT.
// A k-offset = k0 + lk*8 (raw adj pointer); B k-offset = k0 only (bbase already has lk*8).
__global__ __launch_bounds__(256, 3) void k_gemm(const float* __restrict__ adj,
                                                 const u16* __restrict__ SPT,
                                                 const float* __restrict__ dinv,
                                                 float* __restrict__ accbuf) {
    const int mt = blockIdx.x, nt = blockIdx.y, ks = blockIdx.z;
    const int t = threadIdx.x;
    const int lane = t & 63, w = t >> 6;
    const int lrow = lane & 15, lk = lane >> 4;
    const int row0 = mt * 256 + w * 64;
    const int n0 = nt * 64;

    const int base = NSTEPS / NSP, extra = NSTEPS % NSP;
    const int s0 = ks * base + (ks < extra ? ks : extra);
    const int s1 = s0 + base + (ks < extra ? 1 : 0);

    const u16* bbase = SPT + (size_t)(n0 + lrow) * NN + lk * 8;   // lane's k-phase built in

    f32x4 acc[4][4] = {};
    const bf16x8 zz = (bf16x8)(__bf16)0.0f;

    for (int s = s0; s < s1; ++s) {
        const int k0 = s * 32;
        const bool kv = (k0 + lk * 8) < NN;          // 8-elem chunks all-or-nothing (NN%8==0)
        const int ka = kv ? (k0 + lk * 8) : 0;       // A: raw pointer, needs lane phase
        const int kb = kv ? k0 : 0;                  // B: bbase already has lane phase

        // A: 4 row-frags x 8 fp32 each, straight from global
        f32x4 a0[4], a1[4];
#pragma unroll
        for (int i = 0; i < 4; ++i) {
            const int row = row0 + i * 16 + lrow;
            const float* ap = adj + (size_t)(row < NN ? row : 0) * NN + ka;
            a0[i] = *reinterpret_cast<const f32x4*>(ap);
            a1[i] = *reinterpret_cast<const f32x4*>(ap + 4);
        }
        // B: 4 col-frags x 16B from SPT (L2)
        uint4 bq[4];
#pragma unroll
        for (int nf = 0; nf < 4; ++nf)
            bq[nf] = *reinterpret_cast<const uint4*>(bbase + (size_t)nf * 16 * NN + kb);

        bf16x8 af[4], bf[4];
#pragma unroll
        for (int i = 0; i < 4; ++i) {
            bf16x8 a;
            a[0] = (__bf16)a0[i][0]; a[1] = (__bf16)a0[i][1];
            a[2] = (__bf16)a0[i][2]; a[3] = (__bf16)a0[i][3];
            a[4] = (__bf16)a1[i][0]; a[5] = (__bf16)a1[i][1];
            a[6] = (__bf16)a1[i][2]; a[7] = (__bf16)a1[i][3];
            af[i] = kv ? a : zz;
            bf[i] = kv ? *reinterpret_cast<const bf16x8*>(&bq[i]) : zz;
        }
#pragma unroll
        for (int i = 0; i < 4; ++i)
#pragma unroll
            for (int j = 0; j < 4; ++j)
                acc[i][j] = __builtin_amdgcn_mfma_f32_16x16x32_bf16(af[i], bf[j], acc[i][j], 0, 0, 0);
    }

    // epilogue: accbuf[row, col] += dinv_row * acc   (C/D: col=lane&15, row=(lane>>4)*4+reg)
#pragma unroll
    for (int i = 0; i < 4; ++i) {
        const int rb = row0 + i * 16 + lk * 4;
#pragma unroll
        for (int r = 0; r < 4; ++r) {
            const int row = rb + r;
            if (row < NN) {
                const float dv = dinv[row];
#pragma unroll
                for (int j = 0; j < 4; ++j)
                    unsafeAtomicAdd(&accbuf[(size_t)row * NF + n0 + j * 16 + lrow],
                                    dv * acc[i][j][r]);
            }
        }
    }
}

// ---------------- kernel 4: out = relu(accbuf) ----------------
__global__ __launch_bounds__(256) void k_relu(const float* __restrict__ accbuf,
                                              float* __restrict__ out) {
    const int stride = gridDim.x * 256;
    for (int e = blockIdx.x * 256 + threadIdx.x; e < NN * NF / 4; e += stride) {
        f32x4 v = reinterpret_cast<const f32x4*>(accbuf)[e];
        f32x4 o;
#pragma unroll
        for (int c = 0; c < 4; ++c) o[c] = fmaxf(v[c], 0.f);
        reinterpret_cast<f32x4*>(out)[e] = o;
    }
}

extern "C" void kernel_launch(void* const* d_in, const int* in_sizes, int n_in,
                              void* d_out, int out_size, void* d_ws, size_t ws_size,
                              hipStream_t stream) {
    const float* adj  = (const float*)d_in[0];
    const float* feat = (const float*)d_in[1];
    const float* W    = (const float*)d_in[2];
    const float* bias = (const float*)d_in[3];
    // d_in[4] (a) is mathematically unused: softmax over a size-1 axis == 1.

    char* ws = (char*)d_ws;
    const size_t SPT_OFF  = 0;              // 256*10000*2 = 5,120,000 B
    const size_t DINV_OFF = 5120000;        // + 40,000 B
    const size_t ACC_OFF  = 5160192;        // 256-aligned; + 10,240,000 B
    u16*   SPT    = (u16*)(ws + SPT_OFF);
    float* dinv   = (float*)(ws + DINV_OFF);
    float* accbuf = (float*)(ws + ACC_OFF);

    k_deg<<<NN, 256, 0, stream>>>(adj, dinv);
    k_support<<<dim3(157, 4), 256, 0, stream>>>(feat, W, dinv, bias, SPT, accbuf);
    k_gemm<<<dim3(40, 4, NSP), 256, 0, stream>>>(adj, SPT, dinv, accbuf);
    k_relu<<<2048, 256, 0, stream>>>(accbuf, (float*)d_out);
}

// Round 5
// 302.767 us; speedup vs baseline: 1.2303x; 1.2303x over previous
//
#include <hip/hip_runtime.h>
#include <hip/hip_bf16.h>
#include <stdint.h>

#define NN 10000
#define NF 256
#define NSTEPS 313   // ceil(10000/32)
#define NSP 8        // K-split factor
#define DEPTH 3      // A-stage ring depth

typedef float f32x4 __attribute__((ext_vector_type(4)));
typedef __bf16 bf16x8 __attribute__((ext_vector_type(8)));
typedef unsigned short u16;

__device__ __forceinline__ u16 f2bf(float f) {
    __bf16 h = (__bf16)f;
    return __builtin_bit_cast(u16, h);
}

// ---------------- kernel 1: deg -> dinv ----------------
__global__ __launch_bounds__(256) void k_deg(const float* __restrict__ adj,
                                             float* __restrict__ dinv) {
    const int row = blockIdx.x;
    const f32x4* rp = reinterpret_cast<const f32x4*>(adj + (size_t)row * NN);
    float s = 0.f;
    for (int j = threadIdx.x; j < NN / 4; j += 256) {
        f32x4 v = rp[j];
        s += (v[0] + v[1]) + (v[2] + v[3]);
    }
#pragma unroll
    for (int off = 32; off > 0; off >>= 1) s += __shfl_down(s, off, 64);
    __shared__ float red[4];
    const int lane = threadIdx.x & 63, w = threadIdx.x >> 6;
    if (lane == 0) red[w] = s;
    __syncthreads();
    if (threadIdx.x == 0) {
        float deg = (red[0] + red[1]) + (red[2] + red[3]);
        dinv[row] = deg > 0.f ? 1.0f / sqrtf(deg) : 0.0f;
    }
}

// ---------------- kernel 2: T = feat @ W; SPT = (dinv*T)^T bf16; acc0 = 2*dinv^2*T + b ----------------
__global__ __launch_bounds__(256) void k_support(const float* __restrict__ feat,
                                                 const float* __restrict__ W,
                                                 const float* __restrict__ dinv,
                                                 const float* __restrict__ bias,
                                                 u16* __restrict__ SPT,
                                                 float* __restrict__ accbuf) {
    const int j0 = blockIdx.x * 64;
    const int c0 = blockIdx.y * 64;
    __shared__ float flds[128][64];   // [f][r] transposed, 32 KB
    const int t = threadIdx.x;
    const int rg = t & 15, cg = t >> 4;
    const int sr = t >> 2, sf = (t & 3) * 32;
    float acc[4][4] = {};

    for (int half = 0; half < 2; ++half) {
        __syncthreads();
        const int gj = j0 + sr;
#pragma unroll
        for (int i = 0; i < 8; ++i) {
            f32x4 v = {};
            if (gj < NN)
                v = *reinterpret_cast<const f32x4*>(&feat[(size_t)gj * NF + half * 128 + sf + i * 4]);
#pragma unroll
            for (int u = 0; u < 4; ++u) flds[sf + i * 4 + u][sr] = v[u];
        }
        __syncthreads();
#pragma unroll 4
        for (int f = 0; f < 128; ++f) {
            f32x4 fv = *reinterpret_cast<const f32x4*>(&flds[f][rg * 4]);
            f32x4 wv = *reinterpret_cast<const f32x4*>(&W[(size_t)(half * 128 + f) * NF + c0 + cg * 4]);
#pragma unroll
            for (int r = 0; r < 4; ++r)
#pragma unroll
                for (int c = 0; c < 4; ++c)
                    acc[r][c] = fmaf(fv[r], wv[c], acc[r][c]);
        }
    }

    const int jb = j0 + rg * 4;
    if (jb < NN) {
        const f32x4 bv = *reinterpret_cast<const f32x4*>(&bias[c0 + cg * 4]);
        u16 bits[4][4];
#pragma unroll
        for (int r = 0; r < 4; ++r) {
            const float dv = dinv[jb + r];
            f32x4 init;
#pragma unroll
            for (int c = 0; c < 4; ++c) {
                const float sp = acc[r][c] * dv;          // S' = dinv_j * T
                bits[r][c] = f2bf(sp);
                init[c] = 2.f * dv * sp + bv[c];          // self-term + bias (fp32)
            }
            *reinterpret_cast<f32x4*>(&accbuf[(size_t)(jb + r) * NF + c0 + cg * 4]) = init;
        }
#pragma unroll
        for (int c = 0; c < 4; ++c) {
            ushort4 v; v.x = bits[0][c]; v.y = bits[1][c]; v.z = bits[2][c]; v.w = bits[3][c];
            *reinterpret_cast<ushort4*>(&SPT[(size_t)(c0 + cg * 4 + c) * NN + jb]) = v;
        }
    }
}

// ---------------- kernel 3: accbuf += dinv_i * adj(tile) @ S' ----------------
// Linear grid 157*8: ks = bid&7 (-> same XCD shares one SPT k-slice in L2), mt = bid>>3.
// Block = 64 rows x full N=256 (A consumed ONCE). A: global_load_lds into 3-deep ring,
// chunk-XOR-swizzled source, counted vmcnt(2) + raw s_barrier per iter (no drain in
// steady state). B: reg double-buffer, 1-iter prefetch lead, from L2-resident SPT.
__global__ __launch_bounds__(256, 3) void k_gemm(const float* __restrict__ adj,
                                                 const u16* __restrict__ SPT,
                                                 const float* __restrict__ dinv,
                                                 float* __restrict__ accbuf) {
    const int bid = blockIdx.x;
    const int ks = bid & 7, mt = bid >> 3;
    const int m0 = mt * 64;
    const int t = threadIdx.x;
    const int lane = t & 63, w = t >> 6;
    const int n0 = w * 64;                       // wave's 64 output cols
    const int lrow = lane & 15, lk = lane >> 4;

    const int base = NSTEPS / NSP, extra = NSTEPS % NSP;
    const int s0 = ks * base + (ks < extra ? ks : extra);
    const int s1 = s0 + base + (ks < extra ? 1 : 0);

    __shared__ __align__(16) float Abuf[DEPTH][2048];   // 3 x 8KB: 64 rows x 32 fp32

    // stage: 256 threads x 2 x 16B; LDS linear dest (wave-uniform base + lane*16B),
    // global source chunk g = (t&7) ^ (r&7) -> swizzled-read is 2-way-conflict-free.
    auto stage = [&](int d, int s) {
#pragma unroll
        for (int is = 0; is < 2; ++is) {
            const int r = (t >> 3) + is * 32;
            const int g = (t & 7) ^ (r & 7);
            const int row = m0 + r;
            const int kc = s * 32 + g * 4;
            const float* src = (row < NN && kc < NN) ? (adj + (size_t)row * NN + kc) : adj;
            __builtin_amdgcn_global_load_lds(
                (const __attribute__((address_space(1))) void*)src,
                (__attribute__((address_space(3))) void*)&Abuf[d][t * 4 + is * 1024],
                16, 0, 0);
        }
    };

    const u16* bbase = SPT + (size_t)(n0 + lrow) * NN + lk * 8;   // lane k-phase built in
    auto loadB = [&](int s, uint4* bq) {
        const int k0 = s * 32;
        const int kb = ((k0 + lk * 8) < NN) ? k0 : 0;   // redirected garbage zeroed at use
#pragma unroll
        for (int nf = 0; nf < 4; ++nf)
            bq[nf] = *reinterpret_cast<const uint4*>(bbase + (size_t)nf * 16 * NN + kb);
    };

    f32x4 acc[4][4] = {};
    uint4 bc[4], bn[4];

    // prologue: B(s0) + stages s0, s0+1  (queue: 4 + 2 + 2 instr)
    loadB(s0, bc);
    stage(0, s0);
    if (s0 + 1 < s1) stage(1, s0 + 1);

    int d_cur = 0;
    for (int s = s0; s < s1; ++s) {
        // wait: allowed-outstanding = stage(s+1) only (2 instr); last iter drains all.
        if (s < s1 - 1) asm volatile("s_waitcnt vmcnt(2)" ::: "memory");
        else            asm volatile("s_waitcnt vmcnt(0)" ::: "memory");
        __builtin_amdgcn_s_barrier();   // all waves' stage(s) landed; prior reads done

        if (s + 1 < s1) loadB(s + 1, bn);
        const int d_stage = (d_cur + 2 >= DEPTH) ? d_cur + 2 - DEPTH : d_cur + 2;
        if (s + 2 < s1) stage(d_stage, s + 2);

        const int k0 = s * 32;
        const bool kv = (k0 + lk * 8) < NN;      // 8-chunk all-or-nothing (NN%8==0)
        const float* ab = Abuf[d_cur];
        const bf16x8 zz = (bf16x8)(__bf16)0.0f;
        bf16x8 af[4], bf[4];
#pragma unroll
        for (int fi = 0; fi < 4; ++fi) {
            const int r = fi * 16 + lrow;
            const int sl0 = (lk * 2) ^ (r & 7);
            const int sl1 = (lk * 2 + 1) ^ (r & 7);
            f32x4 x0 = *reinterpret_cast<const f32x4*>(&ab[r * 32 + sl0 * 4]);
            f32x4 x1 = *reinterpret_cast<const f32x4*>(&ab[r * 32 + sl1 * 4]);
            bf16x8 a;
            a[0] = (__bf16)x0[0]; a[1] = (__bf16)x0[1];
            a[2] = (__bf16)x0[2]; a[3] = (__bf16)x0[3];
            a[4] = (__bf16)x1[0]; a[5] = (__bf16)x1[1];
            a[6] = (__bf16)x1[2]; a[7] = (__bf16)x1[3];
            af[fi] = kv ? a : zz;
            bf[fi] = kv ? *reinterpret_cast<const bf16x8*>(&bc[fi]) : zz;
        }
#pragma unroll
        for (int i = 0; i < 4; ++i)
#pragma unroll
            for (int j = 0; j < 4; ++j)
                acc[i][j] = __builtin_amdgcn_mfma_f32_16x16x32_bf16(af[i], bf[j], acc[i][j], 0, 0, 0);

#pragma unroll
        for (int nf = 0; nf < 4; ++nf) bc[nf] = bn[nf];
        d_cur = (d_cur + 1 == DEPTH) ? 0 : d_cur + 1;
    }

    // epilogue: accbuf[row, col] += dinv_row * acc   (C/D: col=lane&15, row=(lane>>4)*4+reg)
#pragma unroll
    for (int i = 0; i < 4; ++i) {
        const int rb = m0 + i * 16 + lk * 4;
#pragma unroll
        for (int r = 0; r < 4; ++r) {
            const int row = rb + r;
            if (row < NN) {
                const float dv = dinv[row];
#pragma unroll
                for (int j = 0; j < 4; ++j)
                    unsafeAtomicAdd(&accbuf[(size_t)row * NF + n0 + j * 16 + lrow],
                                    dv * acc[i][j][r]);
            }
        }
    }
}

// ---------------- kernel 4: out = relu(accbuf) ----------------
__global__ __launch_bounds__(256) void k_relu(const float* __restrict__ accbuf,
                                              float* __restrict__ out) {
    const int stride = gridDim.x * 256;
    for (int e = blockIdx.x * 256 + threadIdx.x; e < NN * NF / 4; e += stride) {
        f32x4 v = reinterpret_cast<const f32x4*>(accbuf)[e];
        f32x4 o;
#pragma unroll
        for (int c = 0; c < 4; ++c) o[c] = fmaxf(v[c], 0.f);
        reinterpret_cast<f32x4*>(out)[e] = o;
    }
}

extern "C" void kernel_launch(void* const* d_in, const int* in_sizes, int n_in,
                              void* d_out, int out_size, void* d_ws, size_t ws_size,
                              hipStream_t stream) {
    const float* adj  = (const float*)d_in[0];
    const float* feat = (const float*)d_in[1];
    const float* W    = (const float*)d_in[2];
    const float* bias = (const float*)d_in[3];
    // d_in[4] (a) is mathematically unused: softmax over a size-1 axis == 1.

    char* ws = (char*)d_ws;
    const size_t SPT_OFF  = 0;              // 256*10000*2 = 5,120,000 B
    const size_t DINV_OFF = 5120000;        // + 40,000 B
    const size_t ACC_OFF  = 5160192;        // 256-aligned; + 10,240,000 B
    u16*   SPT    = (u16*)(ws + SPT_OFF);
    float* dinv   = (float*)(ws + DINV_OFF);
    float* accbuf = (float*)(ws + ACC_OFF);

    k_deg<<<NN, 256, 0, stream>>>(adj, dinv);
    k_support<<<dim3(157, 4), 256, 0, stream>>>(feat, W, dinv, bias, SPT, accbuf);
    k_gemm<<<157 * NSP, 256, 0, stream>>>(adj, SPT, dinv, accbuf);
    k_relu<<<2048, 256, 0, stream>>>(accbuf, (float*)d_out);
}